// Round 1
// baseline (263.446 us; speedup 1.0000x reference)
//
#include <hip/hip_runtime.h>
#include <hip/hip_bf16.h>
#include <math.h>

// Problem constants
#define NPIX   25600      // H*W = 160*160
#define CDIM   256
#define SSEL   1024       // MAX_SAMPLES
#define BATCH  4
#define NCHUNK 25         // NPIX / 1024
#define INV_T  10.0f      // 1/TEMP
#define RATIO  1.4285714285714286f  // TEMP/BASE_TEMP
#define THR    0.7f
#define NBLK_SIM (136 * BATCH)

typedef __attribute__((ext_vector_type(8))) short bf16x8;
typedef __attribute__((ext_vector_type(4))) float f32x4;
typedef unsigned short u16;

__device__ __forceinline__ u16 to_bf16(float v) {
  __hip_bfloat16 h = __float2bfloat16(v);
  return *reinterpret_cast<u16*>(&h);
}

// ---------------------------------------------------------------------------
// Kernel A: prep. Blocks 0..99: per-(batch,chunk) stable scatter, with chunk
// counts recomputed in-block (labels are L2-resident; removes counts kernel +
// dependency). Blocks 100..163: weight fp32->bf16 pack + accumulator zeroing.
// ---------------------------------------------------------------------------
__global__ __launch_bounds__(1024) void prep_kernel(
    const float* __restrict__ w1, const float* __restrict__ w2,
    const float* __restrict__ wa1,
    const int* __restrict__ labels, const int* __restrict__ sp,
    u16* __restrict__ w1b, u16* __restrict__ w2b, u16* __restrict__ wab,
    float* __restrict__ denom, float* __restrict__ Prow,
    float* __restrict__ Ssum, unsigned* __restrict__ donecnt,
    int* __restrict__ idx, int* __restrict__ selv, int* __restrict__ tsp) {
  __shared__ int wcnt[NCHUNK][16];
  __shared__ int cs[NCHUNK];
  int t = threadIdx.x;
  int blk = blockIdx.x;

  if (blk < BATCH * NCHUNK) {
    int b = blk / NCHUNK, ch = blk % NCHUNK;
    int lane = t & 63, wid = t >> 6;
    int my_isv = 0;
    unsigned long long my_mv = 0;
    // one pass over the whole batch's labels: per-chunk wave counts
    for (int c = 0; c < NCHUNK; ++c) {
      int isv = (labels[b * NPIX + c * 1024 + t] == 1) ? 1 : 0;
      unsigned long long mv = __ballot(isv);
      if (c == ch) { my_isv = isv; my_mv = mv; }
      if (lane == 0) wcnt[c][wid] = __popcll(mv);
    }
    __syncthreads();
    if (t < NCHUNK) {
      int s = 0;
      for (int w = 0; w < 16; ++w) s += wcnt[t][w];
      cs[t] = s;
    }
    __syncthreads();
    int Vtot = 0, vbase = 0;
    for (int c = 0; c < NCHUNK; ++c) {
      int v = cs[c];
      Vtot += v;
      if (c < ch) vbase += v;
    }
    int ibase = ch * 1024 - vbase;
    int pv = __popcll(my_mv & ((1ull << lane) - 1ull));
    for (int w = 0; w < wid; ++w) pv += wcnt[ch][w];
    int i = ch * 1024 + t;
    int gslot = my_isv ? (vbase + pv) : (Vtot + ibase + (t - pv));
    if (gslot < SSEL) {
      idx [b * SSEL + gslot] = i;
      selv[b * SSEL + gslot] = my_isv;
      tsp [b * SSEL + gslot] = sp[b * NPIX + i];
    }
  } else {
    int e = (blk - BATCH * NCHUNK) * 1024 + t;   // 0..65535
    w1b[e] = to_bf16(w1[e]);
    w2b[e] = to_bf16(w2[e]);
    if (e < 16384) wab[e] = to_bf16(wa1[e]);
    if (e < BATCH * SSEL) { denom[e] = 0.f; Prow[e] = 0.f; }
    if (e < BATCH) Ssum[e] = 0.f;
    if (e == 0) *donecnt = 0u;
  }
}

// ---------------------------------------------------------------------------
// Kernel B: fused gather + gemm1(+attn head) + gemm2 + row-norm.
// Grid 64 blocks x 256 threads; block owns 64 rows. x rows gathered from
// feats straight into LDS (bf16); h kept in LDS; weight B-fragments read
// directly from L2-resident bf16 weight arrays (no B staging, no global
// intermediates). Accumulation order matches the previous split kernels
// (K-chunks sequential) -> bit-identical results.
// ---------------------------------------------------------------------------
__global__ __launch_bounds__(256) void mlp_fused(
    const float* __restrict__ feats, const int* __restrict__ idx,
    const u16* __restrict__ w1b, const u16* __restrict__ w2b,
    const u16* __restrict__ wab,
    const float* __restrict__ b1, const float* __restrict__ ba1,
    const float* __restrict__ wa2, const float* __restrict__ ba2,
    const float* __restrict__ b2,
    u16* __restrict__ fnb, float* __restrict__ tw) {
  int i0 = blockIdx.x * 64;
  int b  = i0 >> 10;
  int t  = threadIdx.x;
  int lane = t & 63, w = t >> 6, m = lane & 15, q = lane >> 4;

  __shared__ __align__(16) u16 xs[64 * 264];
  __shared__ __align__(16) u16 hs[64 * 264];
  __shared__ int ridx[64];

  if (t < 64) ridx[t] = idx[i0 + t];
  __syncthreads();

  // Phase 0: gather. thread t = channel; scattered pixel reads, contiguous
  // (conflict-free) LDS row writes.
  const float* fb = feats + ((long)b * CDIM + t) * NPIX;
#pragma unroll 8
  for (int r = 0; r < 64; ++r)
    xs[r * 264 + t] = to_bf16(fb[ridx[r]]);
  __syncthreads();

  // A fragments for this wave's 16 rows (held across both GEMMs' phase 1)
  bf16x8 af[8];
#pragma unroll
  for (int ks = 0; ks < 8; ++ks)
    af[ks] = *(const bf16x8*)&xs[(w * 16 + m) * 264 + ks * 32 + q * 8];

  // Phase 1: h = relu(x @ w1.T + b1); group 4 = attn head -> tw
  for (int g = 0; g < 5; ++g) {
    bool attn = (g == 4);
    const u16* bsrc = attn ? wab : (w1b + g * 64 * 256);
    f32x4 acc[4];
#pragma unroll
    for (int nt = 0; nt < 4; ++nt) acc[nt] = {0.f, 0.f, 0.f, 0.f};
#pragma unroll
    for (int ks = 0; ks < 8; ++ks) {
      int koff = ks * 32 + q * 8;
#pragma unroll
      for (int nt = 0; nt < 4; ++nt) {
        bf16x8 bh = *(const bf16x8*)&bsrc[(nt * 16 + m) * 256 + koff];
        acc[nt] = __builtin_amdgcn_mfma_f32_16x16x32_bf16(af[ks], bh, acc[nt], 0, 0, 0);
      }
    }
    if (!attn) {
#pragma unroll
      for (int nt = 0; nt < 4; ++nt) {
        int col = g * 64 + nt * 16 + m;
        float bb = b1[col];
#pragma unroll
        for (int reg = 0; reg < 4; ++reg)
          hs[(w * 16 + q * 4 + reg) * 264 + col] =
              to_bf16(fmaxf(acc[nt][reg] + bb, 0.f));
      }
    } else {
      float part[4] = {0.f, 0.f, 0.f, 0.f};
#pragma unroll
      for (int nt = 0; nt < 4; ++nt) {
        int ca = nt * 16 + m;
        float bb = ba1[ca], wv = wa2[ca];
#pragma unroll
        for (int reg = 0; reg < 4; ++reg)
          part[reg] += fmaxf(acc[nt][reg] + bb, 0.f) * wv;
      }
      for (int off = 8; off > 0; off >>= 1) {
#pragma unroll
        for (int reg = 0; reg < 4; ++reg)
          part[reg] += __shfl_xor(part[reg], off, 64);
      }
      if (m == 0) {
        float bb2 = ba2[0];
#pragma unroll
        for (int reg = 0; reg < 4; ++reg) {
          int row = i0 + w * 16 + q * 4 + reg;
          tw[row] = 1.f / (1.f + expf(-(part[reg] + bb2)));
        }
      }
    }
  }
  __syncthreads();

  // Phase 2: p = h @ w2.T + b2, fn = p/|p| -> bf16
  bf16x8 hf[8];
#pragma unroll
  for (int ks = 0; ks < 8; ++ks)
    hf[ks] = *(const bf16x8*)&hs[(w * 16 + m) * 264 + ks * 32 + q * 8];

  f32x4 acc2[4][4];
#pragma unroll
  for (int n = 0; n < 4; ++n)
#pragma unroll
    for (int nt = 0; nt < 4; ++nt) acc2[n][nt] = {0.f, 0.f, 0.f, 0.f};

#pragma unroll
  for (int n = 0; n < 4; ++n) {
#pragma unroll
    for (int ks = 0; ks < 8; ++ks) {
      int koff = ks * 32 + q * 8;
#pragma unroll
      for (int nt = 0; nt < 4; ++nt) {
        bf16x8 bh = *(const bf16x8*)&w2b[(n * 64 + nt * 16 + m) * 256 + koff];
        acc2[n][nt] = __builtin_amdgcn_mfma_f32_16x16x32_bf16(hf[ks], bh, acc2[n][nt], 0, 0, 0);
      }
    }
  }

  float ss[4] = {0.f, 0.f, 0.f, 0.f};
#pragma unroll
  for (int n = 0; n < 4; ++n)
#pragma unroll
    for (int nt = 0; nt < 4; ++nt) {
      float bb = b2[n * 64 + nt * 16 + m];
#pragma unroll
      for (int reg = 0; reg < 4; ++reg) {
        float p = acc2[n][nt][reg] + bb;
        acc2[n][nt][reg] = p;
        ss[reg] += p * p;
      }
    }
  for (int off = 8; off > 0; off >>= 1) {
#pragma unroll
    for (int reg = 0; reg < 4; ++reg) ss[reg] += __shfl_xor(ss[reg], off, 64);
  }
  float inv[4];
#pragma unroll
  for (int reg = 0; reg < 4; ++reg)
    inv[reg] = 1.f / fmaxf(sqrtf(ss[reg]), 1e-12f);

#pragma unroll
  for (int n = 0; n < 4; ++n)
#pragma unroll
    for (int nt = 0; nt < 4; ++nt) {
      int col = n * 64 + nt * 16 + m;
#pragma unroll
      for (int reg = 0; reg < 4; ++reg) {
        int row = i0 + w * 16 + q * 4 + reg;
        fnb[row * 256 + col] = to_bf16(acc2[n][nt][reg] * inv[reg]);
      }
    }
}

// ---------------------------------------------------------------------------
// Kernel C: sim = fn @ fn.T (bf16 MFMA), triangular tiles, fused epilogue
// accumulation + (via done-counter) final loss reduction in the last block.
// ---------------------------------------------------------------------------
__global__ __launch_bounds__(256) void sim_kernel(
    const u16* __restrict__ fnb, const float* __restrict__ tw,
    const int* __restrict__ selv, const int* __restrict__ tsp,
    float* __restrict__ denom, float* __restrict__ Prow,
    float* __restrict__ Ssum, unsigned* __restrict__ donecnt,
    float* __restrict__ out) {
  int b = blockIdx.y;
  int t = threadIdx.x;
  int lane = t & 63, w = t >> 6;
  int m = lane & 15, q = lane >> 4;

  int rem = blockIdx.x, ti = 0;
  while (rem >= (16 - ti)) { rem -= (16 - ti); ++ti; }
  int tj = ti + rem;
  bool diag = (ti == tj);
  int i0 = ti * 64, j0 = tj * 64;
  int base = b << 10;

  __shared__ __align__(16) u16 Ah[64 * 264];
  __shared__ __align__(16) u16 Bhh[64 * 264];
  __shared__ float drl[64], Prl[64];
  __shared__ float dclw[4][64], Pclw[4][64];
  __shared__ float swv[4];
  __shared__ unsigned lastv;
  __shared__ float wPf[4][4], wLf[4][4];

  const u16* Bh = diag ? Ah : Bhh;

  // stage full 64x256 tiles once (2 barriers total instead of 8)
#pragma unroll
  for (int p = 0; p < 8; ++p) {
    int e = p * 256 + t;
    int row = e >> 5, kg = e & 31;
    *(uint4*)&Ah[row * 264 + kg * 8] =
        *(const uint4*)&fnb[(base + i0 + row) * 256 + kg * 8];
    if (!diag)
      *(uint4*)&Bhh[row * 264 + kg * 8] =
          *(const uint4*)&fnb[(base + j0 + row) * 256 + kg * 8];
  }
  __syncthreads();

  f32x4 acc[4];
#pragma unroll
  for (int nt = 0; nt < 4; ++nt) acc[nt] = {0.f, 0.f, 0.f, 0.f};
#pragma unroll
  for (int ks = 0; ks < 8; ++ks) {
    int koff = ks * 32 + q * 8;
    bf16x8 ah = *(const bf16x8*)&Ah[(w * 16 + m) * 264 + koff];
#pragma unroll
    for (int nt = 0; nt < 4; ++nt) {
      bf16x8 bh = *(const bf16x8*)&Bh[(nt * 16 + m) * 264 + koff];
      acc[nt] = __builtin_amdgcn_mfma_f32_16x16x32_bf16(ah, bh, acc[nt], 0, 0, 0);
    }
  }

  int   gi[4], gj[4], si[4], sj[4], ci[4], cj[4];
  float twi[4], twj[4];
#pragma unroll
  for (int reg = 0; reg < 4; ++reg) {
    int i = i0 + w * 16 + q * 4 + reg;
    gi[reg] = i; twi[reg] = tw[base + i];
    si[reg] = selv[base + i]; ci[reg] = tsp[base + i];
  }
#pragma unroll
  for (int nt = 0; nt < 4; ++nt) {
    int j = j0 + nt * 16 + m;
    gj[nt] = j; twj[nt] = tw[base + j];
    sj[nt] = selv[base + j]; cj[nt] = tsp[base + j];
  }

  float dR[4] = {0, 0, 0, 0}, PR[4] = {0, 0, 0, 0};
  float dC[4] = {0, 0, 0, 0}, PC[4] = {0, 0, 0, 0};
  float Sp = 0.f;
#pragma unroll
  for (int nt = 0; nt < 4; ++nt) {
#pragma unroll
    for (int reg = 0; reg < 4; ++reg) {
      float s = acc[nt][reg];
      float e10 = __expf(s * INV_T);
      if (sj[nt]) dR[reg] += e10;
      if (si[reg]) dC[nt] += e10;
      if (si[reg] && sj[nt] && (ci[reg] == cj[nt]) && (s > THR) && (gi[reg] != gj[nt])) {
        float pw = twi[reg] * twj[nt];
        PR[reg] += pw;
        PC[nt] += pw;
        Sp += pw * s;
      }
    }
  }

  for (int off = 8; off > 0; off >>= 1) {
#pragma unroll
    for (int reg = 0; reg < 4; ++reg) {
      dR[reg] += __shfl_xor(dR[reg], off, 64);
      PR[reg] += __shfl_xor(PR[reg], off, 64);
    }
  }
  if (m == 0) {
#pragma unroll
    for (int reg = 0; reg < 4; ++reg) {
      drl[w * 16 + q * 4 + reg] = dR[reg];
      Prl[w * 16 + q * 4 + reg] = PR[reg];
    }
  }
  if (!diag) {
    for (int off = 32; off >= 16; off >>= 1) {
#pragma unroll
      for (int nt = 0; nt < 4; ++nt) {
        dC[nt] += __shfl_xor(dC[nt], off, 64);
        PC[nt] += __shfl_xor(PC[nt], off, 64);
      }
    }
    if (q == 0) {
#pragma unroll
      for (int nt = 0; nt < 4; ++nt) {
        dclw[w][nt * 16 + m] = dC[nt];
        Pclw[w][nt * 16 + m] = PC[nt];
      }
    }
  }
  for (int off = 32; off > 0; off >>= 1) Sp += __shfl_xor(Sp, off, 64);
  if (lane == 0) swv[w] = Sp;
  __syncthreads();

  if (t < 64) {
    atomicAdd(&denom[base + i0 + t], drl[t]);
    atomicAdd(&Prow [base + i0 + t], Prl[t]);
    if (!diag) {
      float dc = dclw[0][t] + dclw[1][t] + dclw[2][t] + dclw[3][t];
      float pc = Pclw[0][t] + Pclw[1][t] + Pclw[2][t] + Pclw[3][t];
      atomicAdd(&denom[base + j0 + t], dc);
      atomicAdd(&Prow [base + j0 + t], pc);
    }
  }
  if (t == 0) {
    float St = swv[0] + swv[1] + swv[2] + swv[3];
    atomicAdd(&Ssum[b], diag ? St : 2.f * St);
  }

  // ---- fused finalize: last block to finish reduces the loss -------------
  __threadfence();
  if (t == 0)
    lastv = __hip_atomic_fetch_add(donecnt, 1u, __ATOMIC_ACQ_REL,
                                   __HIP_MEMORY_SCOPE_AGENT);
  __syncthreads();
  if (lastv != NBLK_SIM - 1) return;

  float Pb[4] = {0.f, 0.f, 0.f, 0.f}, Lb[4] = {0.f, 0.f, 0.f, 0.f};
#pragma unroll
  for (int k = 0; k < 16; ++k) {
    int bb = k >> 2;
    int s = bb * SSEL + (k & 3) * 256 + t;
    float p = __hip_atomic_load(&Prow[s], __ATOMIC_RELAXED, __HIP_MEMORY_SCOPE_AGENT);
    float D = __hip_atomic_load(&denom[s], __ATOMIC_RELAXED, __HIP_MEMORY_SCOPE_AGENT);
    Pb[bb] += p;
    Lb[bb] += p * logf(D > 0.f ? D : 1.f);
  }
  for (int off = 32; off > 0; off >>= 1) {
#pragma unroll
    for (int bb = 0; bb < 4; ++bb) {
      Pb[bb] += __shfl_xor(Pb[bb], off, 64);
      Lb[bb] += __shfl_xor(Lb[bb], off, 64);
    }
  }
  if (lane == 0) {
#pragma unroll
    for (int bb = 0; bb < 4; ++bb) { wPf[w][bb] = Pb[bb]; wLf[w][bb] = Lb[bb]; }
  }
  __syncthreads();
  if (t == 0) {
    float total = 0.f, n = 0.f;
    for (int bb = 0; bb < BATCH; ++bb) {
      float psum = wPf[0][bb] + wPf[1][bb] + wPf[2][bb] + wPf[3][bb];
      float lsum = wLf[0][bb] + wLf[1][bb] + wLf[2][bb] + wLf[3][bb];
      float Sb = __hip_atomic_load(&Ssum[bb], __ATOMIC_RELAXED, __HIP_MEMORY_SCOPE_AGENT);
      if (psum > 0.f) {
        float wls = Sb * INV_T - lsum;
        total += -RATIO * wls / psum;
        n += 1.f;
      }
    }
    out[0] = (n > 0.f) ? (total / n) : 0.f;
  }
}

// ---------------------------------------------------------------------------
extern "C" void kernel_launch(void* const* d_in, const int* in_sizes, int n_in,
                              void* d_out, int out_size, void* d_ws, size_t ws_size,
                              hipStream_t stream) {
  const float* feats = (const float*)d_in[0];
  const int*   labels = (const int*)d_in[1];
  const int*   sp     = (const int*)d_in[2];
  const float* w1  = (const float*)d_in[3];
  const float* b1  = (const float*)d_in[4];
  const float* w2  = (const float*)d_in[5];
  const float* b2  = (const float*)d_in[6];
  const float* wa1 = (const float*)d_in[7];
  const float* ba1 = (const float*)d_in[8];
  const float* wa2 = (const float*)d_in[9];
  const float* ba2 = (const float*)d_in[10];
  float* out = (float*)d_out;

  char* W = (char*)d_ws;
  u16* w1b = (u16*)W;               W += 65536 * 2;
  u16* w2b = (u16*)W;               W += 65536 * 2;
  u16* wab = (u16*)W;               W += 16384 * 2;
  u16* fnb = (u16*)W;               W += 1048576 * 2;
  float* tw   = (float*)W;          W += 4096 * 4;
  float* denom= (float*)W;          W += 4096 * 4;
  float* Prow = (float*)W;          W += 4096 * 4;
  float* Ssum = (float*)W;          W += 4 * 4;
  int*   idx  = (int*)W;            W += 4096 * 4;
  int*   selv = (int*)W;            W += 4096 * 4;
  int*   tsp  = (int*)W;            W += 4096 * 4;
  unsigned* donecnt = (unsigned*)W; W += 4;

  prep_kernel<<<BATCH * NCHUNK + 64, 1024, 0, stream>>>(
      w1, w2, wa1, labels, sp, w1b, w2b, wab,
      denom, Prow, Ssum, donecnt, idx, selv, tsp);
  mlp_fused<<<64, 256, 0, stream>>>(feats, idx, w1b, w2b, wab,
                                    b1, ba1, wa2, ba2, b2, fnb, tw);
  sim_kernel<<<dim3(136, BATCH), 256, 0, stream>>>(
      fnb, tw, selv, tsp, denom, Prow, Ssum, donecnt, out);
}

// Round 2
// 189.343 us; speedup vs baseline: 1.3914x; 1.3914x over previous
//
#include <hip/hip_runtime.h>
#include <hip/hip_bf16.h>
#include <math.h>

// Problem constants
#define NPIX   25600      // H*W = 160*160
#define CDIM   256
#define SSEL   1024       // MAX_SAMPLES
#define BATCH  4
#define NCHUNK 25         // NPIX / 1024
#define INV_T  10.0f      // 1/TEMP
#define RATIO  1.4285714285714286f  // TEMP/BASE_TEMP
#define THR    0.7f

typedef __attribute__((ext_vector_type(8))) short bf16x8;
typedef __attribute__((ext_vector_type(4))) float f32x4;
typedef unsigned short u16;

__device__ __forceinline__ u16 to_bf16(float v) {
  __hip_bfloat16 h = __float2bfloat16(v);
  return *reinterpret_cast<u16*>(&h);
}

// ---------------------------------------------------------------------------
// Kernel A: prep. Blocks 0..99: per-(batch,chunk) stable scatter with chunk
// counts recomputed in-block. Blocks 100..163: weight fp32->bf16 pack +
// accumulator zeroing. No fences, no cross-block dependencies.
// ---------------------------------------------------------------------------
__global__ __launch_bounds__(1024) void prep_kernel(
    const float* __restrict__ w1, const float* __restrict__ w2,
    const float* __restrict__ wa1,
    const int* __restrict__ labels, const int* __restrict__ sp,
    u16* __restrict__ w1b, u16* __restrict__ w2b, u16* __restrict__ wab,
    float* __restrict__ denom, float* __restrict__ Prow,
    float* __restrict__ Ssum,
    int* __restrict__ idx, int* __restrict__ selv, int* __restrict__ tsp) {
  __shared__ int wcnt[NCHUNK][16];
  __shared__ int cs[NCHUNK];
  int t = threadIdx.x;
  int blk = blockIdx.x;

  if (blk < BATCH * NCHUNK) {
    int b = blk / NCHUNK, ch = blk % NCHUNK;
    int lane = t & 63, wid = t >> 6;
    int my_isv = 0;
    unsigned long long my_mv = 0;
    for (int c = 0; c < NCHUNK; ++c) {
      int isv = (labels[b * NPIX + c * 1024 + t] == 1) ? 1 : 0;
      unsigned long long mv = __ballot(isv);
      if (c == ch) { my_isv = isv; my_mv = mv; }
      if (lane == 0) wcnt[c][wid] = __popcll(mv);
    }
    __syncthreads();
    if (t < NCHUNK) {
      int s = 0;
      for (int w = 0; w < 16; ++w) s += wcnt[t][w];
      cs[t] = s;
    }
    __syncthreads();
    int Vtot = 0, vbase = 0;
    for (int c = 0; c < NCHUNK; ++c) {
      int v = cs[c];
      Vtot += v;
      if (c < ch) vbase += v;
    }
    int ibase = ch * 1024 - vbase;
    int pv = __popcll(my_mv & ((1ull << lane) - 1ull));
    for (int w = 0; w < wid; ++w) pv += wcnt[ch][w];
    int i = ch * 1024 + t;
    int gslot = my_isv ? (vbase + pv) : (Vtot + ibase + (t - pv));
    if (gslot < SSEL) {
      idx [b * SSEL + gslot] = i;
      selv[b * SSEL + gslot] = my_isv;
      tsp [b * SSEL + gslot] = sp[b * NPIX + i];
    }
  } else {
    int e = (blk - BATCH * NCHUNK) * 1024 + t;   // 0..65535
    w1b[e] = to_bf16(w1[e]);
    w2b[e] = to_bf16(w2[e]);
    if (e < 16384) wab[e] = to_bf16(wa1[e]);
    if (e < BATCH * SSEL) { denom[e] = 0.f; Prow[e] = 0.f; }
    if (e < BATCH) Ssum[e] = 0.f;
  }
}

// ---------------------------------------------------------------------------
// Kernel B: fused gather + gemm1(+attn) + gemm2 + row-norm.
// 256 blocks x 256 threads, each block owns 16 rows (full-chip TLP for the
// scattered gather, same as the round-0 standalone gather_cast). GEMM N-dim
// is split across the 4 waves (wave w -> cols w*64..w*64+63 for gemm2;
// gemm1 groups g = w, w+4). Weight B-fragments read directly from the
// L2-resident bf16 weight arrays. K-accumulation order identical to the
// split kernels -> numerics preserved.
// ---------------------------------------------------------------------------
__global__ __launch_bounds__(256) void mlp_fused(
    const float* __restrict__ feats, const int* __restrict__ idx,
    const u16* __restrict__ w1b, const u16* __restrict__ w2b,
    const u16* __restrict__ wab,
    const float* __restrict__ b1, const float* __restrict__ ba1,
    const float* __restrict__ wa2, const float* __restrict__ ba2,
    const float* __restrict__ b2,
    u16* __restrict__ fnb, float* __restrict__ tw) {
  int i0 = blockIdx.x * 16;
  int b  = i0 >> 10;
  int t  = threadIdx.x;
  int lane = t & 63, w = t >> 6, m = lane & 15, q = lane >> 4;

  __shared__ __align__(16) u16 xs[16 * 264];
  __shared__ __align__(16) u16 hs[16 * 264];
  __shared__ int ridx[16];
  __shared__ float ssl[4][16];

  if (t < 16) ridx[t] = idx[i0 + t];
  __syncthreads();

  // Phase 0: gather. thread t = channel; 16 scattered pixel reads/thread.
  const float* fb = feats + ((long)b * CDIM + t) * NPIX;
#pragma unroll
  for (int r = 0; r < 16; ++r)
    xs[r * 264 + t] = to_bf16(fb[ridx[r]]);
  __syncthreads();

  // A fragments for the block's 16 rows (shared by all waves)
  bf16x8 af[8];
#pragma unroll
  for (int ks = 0; ks < 8; ++ks)
    af[ks] = *(const bf16x8*)&xs[m * 264 + ks * 32 + q * 8];

  // Phase 1: h = relu(x @ w1.T + b1); group 4 = attn head -> tw.
  for (int g = w; g < 5; g += 4) {
    bool attn = (g == 4);
    const u16* bsrc = attn ? wab : (w1b + g * 64 * 256);
    f32x4 acc[4];
#pragma unroll
    for (int nt = 0; nt < 4; ++nt) acc[nt] = {0.f, 0.f, 0.f, 0.f};
#pragma unroll
    for (int ks = 0; ks < 8; ++ks) {
      int koff = ks * 32 + q * 8;
#pragma unroll
      for (int nt = 0; nt < 4; ++nt) {
        bf16x8 bh = *(const bf16x8*)&bsrc[(nt * 16 + m) * 256 + koff];
        acc[nt] = __builtin_amdgcn_mfma_f32_16x16x32_bf16(af[ks], bh, acc[nt], 0, 0, 0);
      }
    }
    if (!attn) {
#pragma unroll
      for (int nt = 0; nt < 4; ++nt) {
        int col = g * 64 + nt * 16 + m;
        float bb = b1[col];
#pragma unroll
        for (int reg = 0; reg < 4; ++reg)
          hs[(q * 4 + reg) * 264 + col] = to_bf16(fmaxf(acc[nt][reg] + bb, 0.f));
      }
    } else {
      float part[4] = {0.f, 0.f, 0.f, 0.f};
#pragma unroll
      for (int nt = 0; nt < 4; ++nt) {
        int ca = nt * 16 + m;
        float bb = ba1[ca], wv = wa2[ca];
#pragma unroll
        for (int reg = 0; reg < 4; ++reg)
          part[reg] += fmaxf(acc[nt][reg] + bb, 0.f) * wv;
      }
      for (int off = 8; off > 0; off >>= 1) {
#pragma unroll
        for (int reg = 0; reg < 4; ++reg)
          part[reg] += __shfl_xor(part[reg], off, 64);
      }
      if (m == 0) {
        float bb2 = ba2[0];
#pragma unroll
        for (int reg = 0; reg < 4; ++reg)
          tw[i0 + q * 4 + reg] = 1.f / (1.f + expf(-(part[reg] + bb2)));
      }
    }
  }
  __syncthreads();

  // Phase 2: p = h @ w2.T + b2, fn = p/|p| -> bf16. Wave w -> cols w*64..
  bf16x8 hf[8];
#pragma unroll
  for (int ks = 0; ks < 8; ++ks)
    hf[ks] = *(const bf16x8*)&hs[m * 264 + ks * 32 + q * 8];

  f32x4 acc2[4];
#pragma unroll
  for (int nt = 0; nt < 4; ++nt) acc2[nt] = {0.f, 0.f, 0.f, 0.f};
#pragma unroll
  for (int ks = 0; ks < 8; ++ks) {
    int koff = ks * 32 + q * 8;
#pragma unroll
    for (int nt = 0; nt < 4; ++nt) {
      bf16x8 bh = *(const bf16x8*)&w2b[(w * 64 + nt * 16 + m) * 256 + koff];
      acc2[nt] = __builtin_amdgcn_mfma_f32_16x16x32_bf16(hf[ks], bh, acc2[nt], 0, 0, 0);
    }
  }

  // bias + partial row sum-of-squares over this wave's 64 cols
  float ss[4] = {0.f, 0.f, 0.f, 0.f};
#pragma unroll
  for (int nt = 0; nt < 4; ++nt) {
    float bb = b2[w * 64 + nt * 16 + m];
#pragma unroll
    for (int reg = 0; reg < 4; ++reg) {
      float p = acc2[nt][reg] + bb;
      acc2[nt][reg] = p;
      ss[reg] += p * p;
    }
  }
  for (int off = 8; off > 0; off >>= 1) {
#pragma unroll
    for (int reg = 0; reg < 4; ++reg) ss[reg] += __shfl_xor(ss[reg], off, 64);
  }
  if (m == 0) {
#pragma unroll
    for (int reg = 0; reg < 4; ++reg) ssl[w][q * 4 + reg] = ss[reg];
  }
  __syncthreads();

  float inv[4];
#pragma unroll
  for (int reg = 0; reg < 4; ++reg) {
    int row = q * 4 + reg;
    float tot = ssl[0][row] + ssl[1][row] + ssl[2][row] + ssl[3][row];
    inv[reg] = 1.f / fmaxf(sqrtf(tot), 1e-12f);
  }

#pragma unroll
  for (int nt = 0; nt < 4; ++nt) {
    int col = w * 64 + nt * 16 + m;
#pragma unroll
    for (int reg = 0; reg < 4; ++reg)
      fnb[(i0 + q * 4 + reg) * 256 + col] = to_bf16(acc2[nt][reg] * inv[reg]);
  }
}

// ---------------------------------------------------------------------------
// Kernel C: MFMA sim = fn @ fn.T (bf16). Triangular tiles tj>=ti.
// Round-0 proven structure: chunked staging (21KB LDS), plain atomics,
// NO fences.
// ---------------------------------------------------------------------------
__global__ __launch_bounds__(256) void sim_kernel(
    const u16* __restrict__ fnb, const float* __restrict__ tw,
    const int* __restrict__ selv, const int* __restrict__ tsp,
    float* __restrict__ denom, float* __restrict__ Prow, float* __restrict__ Ssum) {
  int b = blockIdx.y;
  int t = threadIdx.x;
  int lane = t & 63, w = t >> 6;
  int m = lane & 15, q = lane >> 4;

  int rem = blockIdx.x, ti = 0;
  while (rem >= (16 - ti)) { rem -= (16 - ti); ++ti; }
  int tj = ti + rem;
  bool diag = (ti == tj);
  int i0 = ti * 64, j0 = tj * 64;
  int base = b << 10;

  __shared__ __align__(16) u16 Ah[64 * 72];
  __shared__ __align__(16) u16 Bhh[64 * 72];
  __shared__ float drl[64], Prl[64];
  __shared__ float dclw[4][64], Pclw[4][64];
  __shared__ float swv[4];

  const u16* Bh = diag ? Ah : Bhh;

  f32x4 acc[4];
#pragma unroll
  for (int nt = 0; nt < 4; ++nt) acc[nt] = {0.f, 0.f, 0.f, 0.f};

  for (int kk = 0; kk < 4; ++kk) {
    __syncthreads();
#pragma unroll
    for (int p = 0; p < 2; ++p) {
      int e = p * 256 + t;
      int row = e >> 3, kg = e & 7;
      int lo = row * 72 + kg * 8;
      *(uint4*)&Ah[lo] = *(const uint4*)&fnb[(base + i0 + row) * 256 + kk * 64 + kg * 8];
      if (!diag)
        *(uint4*)&Bhh[lo] = *(const uint4*)&fnb[(base + j0 + row) * 256 + kk * 64 + kg * 8];
    }
    __syncthreads();
#pragma unroll
    for (int ks = 0; ks < 2; ++ks) {
      int koff = ks * 32 + q * 8;
      bf16x8 ah = *(const bf16x8*)&Ah[(w * 16 + m) * 72 + koff];
#pragma unroll
      for (int nt = 0; nt < 4; ++nt) {
        bf16x8 bh = *(const bf16x8*)&Bh[(nt * 16 + m) * 72 + koff];
        acc[nt] = __builtin_amdgcn_mfma_f32_16x16x32_bf16(ah, bh, acc[nt], 0, 0, 0);
      }
    }
  }

  int   gi[4], gj[4], si[4], sj[4], ci[4], cj[4];
  float twi[4], twj[4];
#pragma unroll
  for (int reg = 0; reg < 4; ++reg) {
    int i = i0 + w * 16 + q * 4 + reg;
    gi[reg] = i; twi[reg] = tw[base + i];
    si[reg] = selv[base + i]; ci[reg] = tsp[base + i];
  }
#pragma unroll
  for (int nt = 0; nt < 4; ++nt) {
    int j = j0 + nt * 16 + m;
    gj[nt] = j; twj[nt] = tw[base + j];
    sj[nt] = selv[base + j]; cj[nt] = tsp[base + j];
  }

  float dR[4] = {0, 0, 0, 0}, PR[4] = {0, 0, 0, 0};
  float dC[4] = {0, 0, 0, 0}, PC[4] = {0, 0, 0, 0};
  float Sp = 0.f;
#pragma unroll
  for (int nt = 0; nt < 4; ++nt) {
#pragma unroll
    for (int reg = 0; reg < 4; ++reg) {
      float s = acc[nt][reg];
      float e10 = __expf(s * INV_T);
      if (sj[nt]) dR[reg] += e10;
      if (si[reg]) dC[nt] += e10;
      if (si[reg] && sj[nt] && (ci[reg] == cj[nt]) && (s > THR) && (gi[reg] != gj[nt])) {
        float pw = twi[reg] * twj[nt];
        PR[reg] += pw;
        PC[nt] += pw;
        Sp += pw * s;
      }
    }
  }

  for (int off = 8; off > 0; off >>= 1) {
#pragma unroll
    for (int reg = 0; reg < 4; ++reg) {
      dR[reg] += __shfl_xor(dR[reg], off, 64);
      PR[reg] += __shfl_xor(PR[reg], off, 64);
    }
  }
  if (m == 0) {
#pragma unroll
    for (int reg = 0; reg < 4; ++reg) {
      drl[w * 16 + q * 4 + reg] = dR[reg];
      Prl[w * 16 + q * 4 + reg] = PR[reg];
    }
  }
  if (!diag) {
    for (int off = 32; off >= 16; off >>= 1) {
#pragma unroll
      for (int nt = 0; nt < 4; ++nt) {
        dC[nt] += __shfl_xor(dC[nt], off, 64);
        PC[nt] += __shfl_xor(PC[nt], off, 64);
      }
    }
    if (q == 0) {
#pragma unroll
      for (int nt = 0; nt < 4; ++nt) {
        dclw[w][nt * 16 + m] = dC[nt];
        Pclw[w][nt * 16 + m] = PC[nt];
      }
    }
  }
  for (int off = 32; off > 0; off >>= 1) Sp += __shfl_xor(Sp, off, 64);
  if (lane == 0) swv[w] = Sp;
  __syncthreads();

  if (t < 64) {
    atomicAdd(&denom[base + i0 + t], drl[t]);
    atomicAdd(&Prow [base + i0 + t], Prl[t]);
    if (!diag) {
      float dc = dclw[0][t] + dclw[1][t] + dclw[2][t] + dclw[3][t];
      float pc = Pclw[0][t] + Pclw[1][t] + Pclw[2][t] + Pclw[3][t];
      atomicAdd(&denom[base + j0 + t], dc);
      atomicAdd(&Prow [base + j0 + t], pc);
    }
  }
  if (t == 0) {
    float St = swv[0] + swv[1] + swv[2] + swv[3];
    atomicAdd(&Ssum[b], diag ? St : 2.f * St);
  }
}

// ---------------------------------------------------------------------------
// Kernel D: finalize. loss_b = -(T/BT) * (S_b/T - sum_i P_i log D_i) / psum_b
// ---------------------------------------------------------------------------
__global__ __launch_bounds__(1024) void finalize_kernel(
    const float* __restrict__ denom, const float* __restrict__ Prow,
    const float* __restrict__ Ssum, float* __restrict__ out) {
  int t = threadIdx.x;
  int b = t >> 8, u = t & 255;
  float P = 0.f, L = 0.f;
#pragma unroll
  for (int q = 0; q < 4; ++q) {
    int s = u + q * 256;
    float p = Prow[b * SSEL + s];
    float D = denom[b * SSEL + s];
    P += p;
    L += p * logf(D > 0.f ? D : 1.f);
  }
  for (int off = 32; off > 0; off >>= 1) {
    P += __shfl_xor(P, off, 64);
    L += __shfl_xor(L, off, 64);
  }
  __shared__ float wP[16], wL[16];
  int lane = t & 63, w = t >> 6;
  if (lane == 0) { wP[w] = P; wL[w] = L; }
  __syncthreads();
  if (t == 0) {
    float total = 0.f, n = 0.f;
    for (int bb = 0; bb < BATCH; ++bb) {
      float psum = wP[4 * bb] + wP[4 * bb + 1] + wP[4 * bb + 2] + wP[4 * bb + 3];
      float lsum = wL[4 * bb] + wL[4 * bb + 1] + wL[4 * bb + 2] + wL[4 * bb + 3];
      if (psum > 0.f) {
        float wls = Ssum[bb] * INV_T - lsum;
        total += -RATIO * wls / psum;
        n += 1.f;
      }
    }
    out[0] = (n > 0.f) ? (total / n) : 0.f;
  }
}

// ---------------------------------------------------------------------------
extern "C" void kernel_launch(void* const* d_in, const int* in_sizes, int n_in,
                              void* d_out, int out_size, void* d_ws, size_t ws_size,
                              hipStream_t stream) {
  const float* feats = (const float*)d_in[0];
  const int*   labels = (const int*)d_in[1];
  const int*   sp     = (const int*)d_in[2];
  const float* w1  = (const float*)d_in[3];
  const float* b1  = (const float*)d_in[4];
  const float* w2  = (const float*)d_in[5];
  const float* b2  = (const float*)d_in[6];
  const float* wa1 = (const float*)d_in[7];
  const float* ba1 = (const float*)d_in[8];
  const float* wa2 = (const float*)d_in[9];
  const float* ba2 = (const float*)d_in[10];
  float* out = (float*)d_out;

  char* W = (char*)d_ws;
  u16* w1b = (u16*)W;               W += 65536 * 2;
  u16* w2b = (u16*)W;               W += 65536 * 2;
  u16* wab = (u16*)W;               W += 16384 * 2;
  u16* fnb = (u16*)W;               W += 1048576 * 2;
  float* tw   = (float*)W;          W += 4096 * 4;
  float* denom= (float*)W;          W += 4096 * 4;
  float* Prow = (float*)W;          W += 4096 * 4;
  float* Ssum = (float*)W;          W += 4 * 4;
  int*   idx  = (int*)W;            W += 4096 * 4;
  int*   selv = (int*)W;            W += 4096 * 4;
  int*   tsp  = (int*)W;            W += 4096 * 4;

  prep_kernel<<<BATCH * NCHUNK + 64, 1024, 0, stream>>>(
      w1, w2, wa1, labels, sp, w1b, w2b, wab, denom, Prow, Ssum,
      idx, selv, tsp);
  mlp_fused<<<256, 256, 0, stream>>>(feats, idx, w1b, w2b, wab,
                                     b1, ba1, wa2, ba2, b2, fnb, tw);
  sim_kernel<<<dim3(136, BATCH), 256, 0, stream>>>(fnb, tw, selv, tsp,
                                                   denom, Prow, Ssum);
  finalize_kernel<<<1, 1024, 0, stream>>>(denom, Prow, Ssum, out);
}